// Round 1
// baseline (235.206 us; speedup 1.0000x reference)
//
#include <hip/hip_runtime.h>
#include <stdint.h>

typedef unsigned short u16;
typedef __attribute__((ext_vector_type(8))) short short8;
typedef __attribute__((ext_vector_type(4))) float f32x4;

#define NB    16
#define DIM   256
#define NTOK  1024

__device__ __forceinline__ u16 f2b(float f) {
    union { float f; uint32_t u; } v; v.f = f;
    uint32_t u = v.u;
    u += 0x7fffu + ((u >> 16) & 1u);
    return (u16)(u >> 16);
}
__device__ __forceinline__ float b2f(u16 h) {
    union { uint32_t u; float f; } v; v.u = ((uint32_t)h) << 16;
    return v.f;
}
__device__ __forceinline__ uint32_t pack2(float a, float b) {
    return (uint32_t)f2b(a) | ((uint32_t)f2b(b) << 16);
}
__device__ __forceinline__ f32x4 mfma16(short8 a, short8 b, f32x4 c) {
    return __builtin_amdgcn_mfma_f32_16x16x32_bf16(a, b, c, 0, 0, 0);
}
__device__ __forceinline__ short8 ld8(const u16* p) {
    return *reinterpret_cast<const short8*>(p);
}

// ---------------- Kernel 1: pack x -> xbf (bf16 copy, [C][N]) + nodes (bf16 transpose, [N][C])
__global__ __launch_bounds__(256) void pack_kernel(const float* __restrict__ x,
                                                   u16* __restrict__ xbf,
                                                   u16* __restrict__ nodes) {
    __shared__ float tile[64][65];
    int tid = threadIdx.x;
    int blk = blockIdx.x;          // 1024 blocks
    int b  = blk >> 6;
    int t  = blk & 63;
    int c0 = (t >> 4) << 6;        // 0,64,128,192
    int n0 = (t & 15) << 6;        // 0..960
    const float* xb = x + (size_t)b * (DIM * NTOK);
    u16* xbb = xbf + (size_t)b * (DIM * NTOK);
#pragma unroll
    for (int i = 0; i < 16; i++) {
        int idx = i * 256 + tid;
        int cl = idx >> 6, nl = idx & 63;
        float f = xb[(c0 + cl) * NTOK + n0 + nl];
        tile[cl][nl] = f;
        xbb[(c0 + cl) * NTOK + n0 + nl] = f2b(f);
    }
    __syncthreads();
#pragma unroll
    for (int i = 0; i < 16; i++) {
        int idx = i * 256 + tid;
        int nl = idx >> 6, cl = idx & 63;
        nodes[(size_t)(b * NTOK + n0 + nl) * DIM + c0 + cl] = f2b(tile[cl][nl]);
    }
}

// ---------------- Kernel 2: convert 3 weight matrices to bf16 (proj_w, w1, w2)
__global__ __launch_bounds__(256) void wconv_kernel(const float* __restrict__ a,
                                                    const float* __restrict__ b,
                                                    const float* __restrict__ c,
                                                    u16* __restrict__ o) {
    int i = blockIdx.x * 256 + threadIdx.x;  // 0..196607
    const float* s = (i < 65536) ? a : (i < 131072) ? b : c;
    o[i] = f2b(s[i & 65535]);
}

// ---------------- Kernel 3: q = nodes @ proj_w^T + proj_b  (bf16 out, [N][C])
__global__ __launch_bounds__(256) void proj_kernel(const u16* __restrict__ nodes,
                                                   const u16* __restrict__ wbf,
                                                   const float* __restrict__ pb,
                                                   u16* __restrict__ qb) {
    int lane = threadIdx.x & 63;
    int w = threadIdx.x >> 6;
    int lo = lane & 15, hi = lane >> 4;
    int row0 = blockIdx.x * 64 + w * 16;
    const u16* arow = nodes + (size_t)(row0 + lo) * DIM + hi * 8;
    f32x4 acc[16];
#pragma unroll
    for (int i = 0; i < 16; i++) acc[i] = (f32x4){0.f, 0.f, 0.f, 0.f};
#pragma unroll
    for (int t = 0; t < 8; t++) {
        short8 a = ld8(arow + t * 32);
#pragma unroll
        for (int nf = 0; nf < 16; nf++) {
            short8 bfr = ld8(wbf + (nf * 16 + lo) * DIM + t * 32 + hi * 8);
            acc[nf] = mfma16(a, bfr, acc[nf]);
        }
    }
#pragma unroll
    for (int nf = 0; nf < 16; nf++) {
        int col = nf * 16 + lo;
        float bias = pb[col];
#pragma unroll
        for (int r = 0; r < 4; r++) {
            int row = row0 + hi * 4 + r;
            qb[(size_t)row * DIM + col] = f2b(acc[nf][r] + bias);
        }
    }
}

// ---------------- Kernel 4: flash attention. agg[q][c] = softmax(q q^T/16) @ nodes
// wave-per-16-q-rows; swapped QK^T (S^T frags); PV as agg^T = V^T @ P^T with V^T = xbf.
__global__ __launch_bounds__(256) void attn_kernel(const u16* __restrict__ qb,
                                                   const u16* __restrict__ xbf,
                                                   u16* __restrict__ agg) {
    int lane = threadIdx.x & 63;
    int w = threadIdx.x >> 6;
    int lo = lane & 15, hi = lane >> 4;
    int b  = blockIdx.x & 15;                 // batch-per-XCD-friendly mapping
    int qt = ((blockIdx.x >> 4) << 2) + w;    // 0..63
    int q0 = qt * 16;
    const u16* qbb = qb  + (size_t)b * (NTOK * DIM);
    const u16* xbb = xbf + (size_t)b * (DIM * NTOK);

    short8 bq[8];
#pragma unroll
    for (int t = 0; t < 8; t++)
        bq[t] = ld8(qbb + (size_t)(q0 + lo) * DIM + t * 32 + hi * 8);

    f32x4 acc[16];
#pragma unroll
    for (int i = 0; i < 16; i++) acc[i] = (f32x4){0.f, 0.f, 0.f, 0.f};
    float m = -1e30f, ell = 0.f;

    for (int kv0 = 0; kv0 < NTOK; kv0 += 32) {
        f32x4 s0 = (f32x4){0.f,0.f,0.f,0.f};
        f32x4 s1 = (f32x4){0.f,0.f,0.f,0.f};
        const u16* k0p = qbb + (size_t)(kv0 + lo) * DIM + hi * 8;
        const u16* k1p = k0p + 16 * DIM;
#pragma unroll
        for (int t = 0; t < 8; t++) {
            s0 = mfma16(ld8(k0p + t * 32), bq[t], s0);
            s1 = mfma16(ld8(k1p + t * 32), bq[t], s1);
        }
        float p0[4], p1[4];
        float pm = -1e30f;
#pragma unroll
        for (int r = 0; r < 4; r++) {
            p0[r] = s0[r] * 0.0625f;
            p1[r] = s1[r] * 0.0625f;
            pm = fmaxf(pm, fmaxf(p0[r], p1[r]));
        }
        pm = fmaxf(pm, __shfl_xor(pm, 16));
        pm = fmaxf(pm, __shfl_xor(pm, 32));
        float mnew = fmaxf(m, pm);
        float sc = __expf(m - mnew);
        float psum = 0.f;
#pragma unroll
        for (int r = 0; r < 4; r++) {
            p0[r] = __expf(p0[r] - mnew);
            p1[r] = __expf(p1[r] - mnew);
            psum += p0[r] + p1[r];
        }
        psum += __shfl_xor(psum, 16);
        psum += __shfl_xor(psum, 32);
        ell = ell * sc + psum;
        m = mnew;
#pragma unroll
        for (int i = 0; i < 16; i++) {
            acc[i][0] *= sc; acc[i][1] *= sc; acc[i][2] *= sc; acc[i][3] *= sc;
        }
        // redistribute P (lane holds P[q=lo][kv=4*hi+r (+16)]) into B-fragment layout
        // needed: P[q=lo][kv=8*hi+j], j=0..7
        uint32_t pl0 = pack2(p0[0], p0[1]), ph0 = pack2(p0[2], p0[3]);
        uint32_t pl1 = pack2(p1[0], p1[1]), ph1 = pack2(p1[2], p1[3]);
        int srcA = ((hi & 1) << 5) | lo;   // lane of h-group 2*(hi&1)
        int srcB = srcA + 16;              // h-group 2*(hi&1)+1
        uint32_t w0a = __shfl(pl0, srcA), w0b = __shfl(pl1, srcA);
        uint32_t w1a = __shfl(ph0, srcA), w1b = __shfl(ph1, srcA);
        uint32_t w2a = __shfl(pl0, srcB), w2b = __shfl(pl1, srcB);
        uint32_t w3a = __shfl(ph0, srcB), w3b = __shfl(ph1, srcB);
        bool sel = (hi >= 2);
        union { uint32_t u[4]; short8 v; } pu;
        pu.u[0] = sel ? w0b : w0a;
        pu.u[1] = sel ? w1b : w1a;
        pu.u[2] = sel ? w2b : w2a;
        pu.u[3] = sel ? w3b : w3a;
        short8 pfrag = pu.v;

        const u16* vp = xbb + kv0 + hi * 8;
#pragma unroll
        for (int mf = 0; mf < 16; mf++) {
            short8 a = ld8(vp + (size_t)(mf * 16 + lo) * NTOK);
            acc[mf] = mfma16(a, pfrag, acc[mf]);
        }
    }
    float rinv = 1.f / ell;
#pragma unroll
    for (int mf = 0; mf < 16; mf++) {
        ushort4 st;
        st.x = f2b(acc[mf][0] * rinv);
        st.y = f2b(acc[mf][1] * rinv);
        st.z = f2b(acc[mf][2] * rinv);
        st.w = f2b(acc[mf][3] * rinv);
        *reinterpret_cast<ushort4*>(agg + (size_t)(b * NTOK + q0 + lo) * DIM + mf * 16 + hi * 4) = st;
    }
}

// ---------------- Kernel 5: FFN + residual.
// h = gelu(agg @ w1^T + b1); out^T = w2 @ h^T + b2; y = x + out^T (x layout)
__global__ __launch_bounds__(256) void ffn_kernel(const u16* __restrict__ agg,
                                                  const u16* __restrict__ wbf,
                                                  const float* __restrict__ b1,
                                                  const float* __restrict__ b2,
                                                  const float* __restrict__ x,
                                                  float* __restrict__ out) {
    __shared__ u16 hl[64][264];
    int lane = threadIdx.x & 63;
    int w = threadIdx.x >> 6;
    int lo = lane & 15, hi = lane >> 4;
    int row0 = blockIdx.x * 64;     // 256 blocks
    int rw = row0 + w * 16;
    const u16* w1b = wbf + 65536;
    const u16* w2b = wbf + 131072;

    f32x4 acc[16];
#pragma unroll
    for (int i = 0; i < 16; i++) acc[i] = (f32x4){0.f, 0.f, 0.f, 0.f};
    const u16* arow = agg + (size_t)(rw + lo) * DIM + hi * 8;
#pragma unroll
    for (int t = 0; t < 8; t++) {
        short8 a = ld8(arow + t * 32);
#pragma unroll
        for (int nf = 0; nf < 16; nf++) {
            short8 bfr = ld8(w1b + (nf * 16 + lo) * DIM + t * 32 + hi * 8);
            acc[nf] = mfma16(a, bfr, acc[nf]);
        }
    }
#pragma unroll
    for (int nf = 0; nf < 16; nf++) {
        int f = nf * 16 + lo;
        float bias = b1[f];
#pragma unroll
        for (int r = 0; r < 4; r++) {
            float v = acc[nf][r] + bias;
            float g = 0.5f * v * (1.f + erff(v * 0.70710678f));
            hl[w * 16 + hi * 4 + r][f] = f2b(g);
        }
    }
    __syncthreads();

    f32x4 acc2[16];
#pragma unroll
    for (int i = 0; i < 16; i++) acc2[i] = (f32x4){0.f, 0.f, 0.f, 0.f};
#pragma unroll
    for (int t = 0; t < 8; t++) {
        short8 bh = ld8(&hl[w * 16 + lo][t * 32 + hi * 8]);
#pragma unroll
        for (int mf = 0; mf < 16; mf++) {
            short8 a = ld8(w2b + (mf * 16 + lo) * DIM + t * 32 + hi * 8);
            acc2[mf] = mfma16(a, bh, acc2[mf]);
        }
    }
    int bidx = row0 >> 10;
    int n = (rw & 1023) + lo;
#pragma unroll
    for (int mf = 0; mf < 16; mf++) {
#pragma unroll
        for (int r = 0; r < 4; r++) {
            int co = mf * 16 + hi * 4 + r;
            size_t addr = (size_t)bidx * (DIM * NTOK) + (size_t)co * NTOK + n;
            out[addr] = acc2[mf][r] + b2[co] + x[addr];
        }
    }
}

extern "C" void kernel_launch(void* const* d_in, const int* in_sizes, int n_in,
                              void* d_out, int out_size, void* d_ws, size_t ws_size,
                              hipStream_t stream) {
    const float* x      = (const float*)d_in[0];
    const float* proj_w = (const float*)d_in[1];
    const float* proj_b = (const float*)d_in[2];
    const float* w1     = (const float*)d_in[3];
    const float* b1     = (const float*)d_in[4];
    const float* w2     = (const float*)d_in[5];
    const float* b2     = (const float*)d_in[6];
    float* out = (float*)d_out;

    u16* xbf   = (u16*)d_ws;                 // 16*256*1024 = 4,194,304 elems
    u16* nodes = xbf   + 4194304;
    u16* qb    = nodes + 4194304;
    u16* agg   = qb    + 4194304;
    u16* wbf   = agg   + 4194304;            // 3*65536 elems

    pack_kernel <<<1024, 256, 0, stream>>>(x, xbf, nodes);
    wconv_kernel<<<768,  256, 0, stream>>>(proj_w, w1, w2, wbf);
    proj_kernel <<<256,  256, 0, stream>>>(nodes, wbf, proj_b, qb);
    attn_kernel <<<256,  256, 0, stream>>>(qb, xbf, agg);
    ffn_kernel  <<<256,  256, 0, stream>>>(agg, wbf, b1, b2, x, out);
}